// Round 7
// baseline (351.481 us; speedup 1.0000x reference)
//
#include <hip/hip_runtime.h>
#include <stdint.h>

#define T_SEQ 8192
#define DMODEL 512
#define QKV_LD 1536   // row stride (elements) of fused QKV output

typedef __attribute__((ext_vector_type(8))) short bfx8;   // 8 bf16 (raw bits) = 4 VGPR
typedef __attribute__((ext_vector_type(4))) float fx4;    // MFMA acc

__device__ __forceinline__ unsigned short f2bf(float f) {
    uint32_t u = __float_as_uint(f);
    u += 0x7fffu + ((u >> 16) & 1u);     // round-to-nearest-even
    return (unsigned short)(u >> 16);
}
__device__ __forceinline__ float bf2f(unsigned short s) {
    return __uint_as_float(((uint32_t)s) << 16);
}

// async global->LDS, 16B per lane; LDS dest is wave-uniform base + lane*16 (HW)
__device__ __forceinline__ void gload16(const void* g, void* l) {
    __builtin_amdgcn_global_load_lds(
        (const __attribute__((address_space(1))) unsigned int*)g,
        (__attribute__((address_space(3))) unsigned int*)l,
        16, 0, 0);
}

__device__ __forceinline__ void fence_barrier() {
    asm volatile("" ::: "memory");
    __builtin_amdgcn_s_barrier();
    asm volatile("" ::: "memory");
}

// ---------------- weight conversion f32 -> bf16 ----------------
__global__ __launch_bounds__(256) void cvt_bf16_kernel(const float* __restrict__ src,
                                                       unsigned short* __restrict__ dst, int n) {
    int i = (blockIdx.x * 256 + threadIdx.x) * 8;
    if (i >= n) return;
    fx4 a = *(const fx4*)(src + i);
    fx4 b = *(const fx4*)(src + i + 4);
    bfx8 o;
    o[0] = f2bf(a[0]); o[1] = f2bf(a[1]); o[2] = f2bf(a[2]); o[3] = f2bf(a[3]);
    o[4] = f2bf(b[0]); o[5] = f2bf(b[1]); o[6] = f2bf(b[2]); o[7] = f2bf(b[3]);
    *(bfx8*)(dst + i) = o;
}

// ---------------- LayerNorm (one wave per row) ----------------
__global__ __launch_bounds__(256) void layernorm_kernel(const float* __restrict__ h,
                                                        const float* __restrict__ w,
                                                        const float* __restrict__ b,
                                                        unsigned short* __restrict__ out) {
    int wv = threadIdx.x >> 6, lane = threadIdx.x & 63;
    int row = blockIdx.x * 4 + wv;
    const float* hr = h + (size_t)row * DMODEL + lane * 8;
    fx4 x0 = *(const fx4*)hr;
    fx4 x1 = *(const fx4*)(hr + 4);
    float s  = x0[0]+x0[1]+x0[2]+x0[3]+x1[0]+x1[1]+x1[2]+x1[3];
    float ss = x0[0]*x0[0]+x0[1]*x0[1]+x0[2]*x0[2]+x0[3]*x0[3]
             + x1[0]*x1[0]+x1[1]*x1[1]+x1[2]*x1[2]+x1[3]*x1[3];
    #pragma unroll
    for (int m = 1; m < 64; m <<= 1) { s += __shfl_xor(s, m); ss += __shfl_xor(ss, m); }
    float mu  = s * (1.0f / DMODEL);
    float var = ss * (1.0f / DMODEL) - mu * mu;
    float r = rsqrtf(var + 1e-5f);
    const float* wp = w + lane * 8; const float* bp = b + lane * 8;
    fx4 w0 = *(const fx4*)wp, w1 = *(const fx4*)(wp + 4);
    fx4 b0 = *(const fx4*)bp, b1 = *(const fx4*)(bp + 4);
    bfx8 o;
    o[0] = f2bf((x0[0]-mu)*r*w0[0] + b0[0]);
    o[1] = f2bf((x0[1]-mu)*r*w0[1] + b0[1]);
    o[2] = f2bf((x0[2]-mu)*r*w0[2] + b0[2]);
    o[3] = f2bf((x0[3]-mu)*r*w0[3] + b0[3]);
    o[4] = f2bf((x1[0]-mu)*r*w1[0] + b1[0]);
    o[5] = f2bf((x1[1]-mu)*r*w1[1] + b1[1]);
    o[6] = f2bf((x1[2]-mu)*r*w1[2] + b1[2]);
    o[7] = f2bf((x1[3]-mu)*r*w1[3] + b1[3]);
    *(bfx8*)(out + (size_t)row * DMODEL + lane * 8) = o;
}

// ---------------- C = A @ B^T  (both [rows][K] bf16), 128x128 tile ----------------
template<int RESID>
__global__ __launch_bounds__(256, 2) void gemm_bt_kernel(
    const unsigned short* __restrict__ A,   // [M][K]
    const unsigned short* __restrict__ B,   // [N][K]
    unsigned short* __restrict__ Cb,
    float* __restrict__ Cf,
    const float* __restrict__ resid,
    int M, int N, int K)
{
    __shared__ unsigned short At[128 * 64];
    __shared__ unsigned short Bt[128 * 64];
    int tid = threadIdx.x;
    int wv = tid >> 6, lane = tid & 63, l15 = lane & 15, l4 = lane >> 4;
    int wr = wv >> 1, wc = wv & 1;
    int row0 = blockIdx.y * 128;
    int col0 = blockIdx.x * 128;
    fx4 acc[4][4] = {};
    const char* Abase = (const char*)(A + (size_t)row0 * K);
    const char* Bbase = (const char*)(B + (size_t)col0 * K);
    for (int kt = 0; kt < K; kt += 64) {
        #pragma unroll
        for (int ch = 0; ch < 4; ch++) {
            int bix = (ch * 256 + tid) * 16;
            int r = bix >> 7;
            int sb = (bix & 127) ^ ((r & 7) << 4);
            bfx8 va = *(const bfx8*)(Abase + (size_t)r * (K * 2) + kt * 2 + sb);
            bfx8 vb = *(const bfx8*)(Bbase + (size_t)r * (K * 2) + kt * 2 + sb);
            *(bfx8*)((char*)At + bix) = va;
            *(bfx8*)((char*)Bt + bix) = vb;
        }
        __syncthreads();
        #pragma unroll
        for (int ks = 0; ks < 2; ks++) {
            bfx8 af[4], bf[4];
            #pragma unroll
            for (int m = 0; m < 4; m++) {
                int ra = wr * 64 + m * 16 + l15;
                int ka = (ks * 64 + l4 * 16) ^ ((ra & 7) << 4);
                af[m] = *(const bfx8*)((const char*)At + ra * 128 + ka);
                int rb = wc * 64 + m * 16 + l15;
                int kb = (ks * 64 + l4 * 16) ^ ((rb & 7) << 4);
                bf[m] = *(const bfx8*)((const char*)Bt + rb * 128 + kb);
            }
            #pragma unroll
            for (int m = 0; m < 4; m++)
                #pragma unroll
                for (int n = 0; n < 4; n++)
                    acc[m][n] = __builtin_amdgcn_mfma_f32_16x16x32_bf16(af[m], bf[n], acc[m][n], 0, 0, 0);
        }
        __syncthreads();
    }
    #pragma unroll
    for (int m = 0; m < 4; m++)
        #pragma unroll
        for (int n = 0; n < 4; n++)
            #pragma unroll
            for (int r = 0; r < 4; r++) {
                int row = row0 + wr * 64 + m * 16 + l4 * 4 + r;
                int col = col0 + wc * 64 + n * 16 + l15;
                float v = acc[m][n][r];
                size_t o = (size_t)row * N + col;
                if (RESID) Cf[o] = v + resid[o];
                else       Cb[o] = f2bf(v);
            }
}

// ---------------- transpose V [T][ld] -> Vt [D][T] (V = cols 0..511 of src) ----------------
__global__ __launch_bounds__(256) void transpose_kernel(const unsigned short* __restrict__ v,
                                                        unsigned short* __restrict__ vt, int ld) {
    __shared__ unsigned short tile[64][80];
    int t = threadIdx.x;
    int r0 = blockIdx.x * 64;   // T dim
    int c0 = blockIdx.y * 64;   // D dim
    int r = t >> 2, cw = (t & 3) * 16;
    const unsigned short* src = v + (size_t)(r0 + r) * ld + c0 + cw;
    bfx8 a = *(const bfx8*)src;
    bfx8 b = *(const bfx8*)(src + 8);
    #pragma unroll
    for (int j = 0; j < 8; j++) { tile[r][cw + j] = a[j]; tile[r][cw + 8 + j] = b[j]; }
    __syncthreads();
    int dc = t >> 2, rb = (t & 3) * 16;
    bfx8 o0, o1;
    #pragma unroll
    for (int j = 0; j < 8; j++) { o0[j] = tile[rb + j][dc]; o1[j] = tile[rb + 8 + j][dc]; }
    unsigned short* dst = vt + (size_t)(c0 + dc) * T_SEQ + r0 + rb;
    *(bfx8*)dst = o0;
    *(bfx8*)(dst + 8) = o1;
}

// ---------------- flash attention v5: V from global (L2), dedicated K buffer ----------------
// QBLK=64 rows/block, 512 threads (8 waves), KVBLK=64.
// QK^T roles: wave=(s,hh): S rows [16s,16s+16), kv cols [32hh,32hh+32).
// PV roles:   wave=(g,cc): O rows [32g,32g+32), d-cols [128cc,128cc+128).
// R6 lesson: K/V time-sharing one LDS buffer exposed the full K-stage latency
// at B1 every iter (stageK could only issue after PV/B4). Now V is NOT staged:
// PV B-frags are 16B-contiguous in Vt and L2-hot (chunk-major order), so V is
// loaded global->VGPR (vf0 hoisted under softmax, vf1 inline in PV). K gets a
// dedicated buffer; stageK(it+1) issues right after B2 -> hidden under
// softmax+PV. 3 barriers/iter (B4 removed: p_lds read/write separated by B1).
// Q/K rows live in the fused QKV buffer with row stride QKV_LD.
__global__ __launch_bounds__(512)
void flash4_kernel(
    const unsigned short* __restrict__ q,      // rows stride QKV_LD, cols 0..511
    const unsigned short* __restrict__ k,      // rows stride QKV_LD, cols 0..511
    const unsigned short* __restrict__ vt,     // [DMODEL][T_SEQ]
    unsigned short* __restrict__ opart,        // [NBLK][64][512] bf16 unnormalized
    float* __restrict__ mbuf, float* __restrict__ lbuf,   // [NBLK][64]
    int CH, int NBLK)                          // CH = kv tiles (64 rows) per chunk
{
    __shared__ unsigned short Q_lds[64 * 512];   // 64 KB, rows of 1024B, XOR-swizzled
    __shared__ unsigned short K_lds[64 * 512];   // 64 KB, rows of 1024B, XOR-swizzled
    __shared__ unsigned short p_lds[64 * 64];    // 8 KB
    __shared__ float red_lds[4][2][16];
    __shared__ float alpha_lds[64];

    int tid = threadIdx.x;
    int wv = tid >> 6, lane = tid & 63, l15 = lane & 15, l4 = lane >> 4;

    // XCD-chunked bijective swizzle (NBLK % 8 == 0)
    int L = blockIdx.x;
    int bid = (L & 7) * (NBLK >> 3) + (L >> 3);

    // decode chunk-major: cum(c) = 128c - CH*c*(c-1)/2 ; count(c) = 128 - CH*c
    int c = 0;
    while (bid >= 128 * (c + 1) - CH * (c + 1) * c / 2) c++;
    int qi = CH * c + (bid - (128 * c - CH * c * (c - 1) / 2));
    int R0 = qi * 64;
    int kv_begin = c * CH * 64;
    int kv_end = min(kv_begin + CH * 64, R0 + 64);
    int ntile = (kv_end - kv_begin) >> 6;

    int s = wv >> 1, hh = wv & 1;     // QK^T roles
    int g = wv & 1, cc = wv >> 1;     // PV roles

    fx4 acc[2][8] = {};
    float m_run[4], l_half[4];
    #pragma unroll
    for (int r = 0; r < 4; r++) { m_run[r] = -INFINITY; l_half[r] = 0.f; }

    const float rscale = 0.044194173824159216f;  // 1/sqrt(512)

    // --- staging: pre-swizzled global source, linear LDS dest (8 loads/wave each) ---
    auto stageQ = [&]() {
        const char* qb = (const char*)q + (size_t)R0 * (QKV_LD * 2);
        #pragma unroll
        for (int j = 0; j < 8; j++) {
            int seg = wv * 8 + j;                 // Q row (1024B of data, stride 3072B)
            int sw = (seg & 7) << 4;
            const char* gp = qb + (size_t)seg * (QKV_LD * 2) + ((lane * 16) ^ sw);
            gload16(gp, (char*)Q_lds + seg * 1024);
        }
    };
    auto stageK = [&](int kv0) {
        const char* kb = (const char*)k + (size_t)kv0 * (QKV_LD * 2);
        #pragma unroll
        for (int j = 0; j < 8; j++) {
            int seg = wv * 8 + j;                 // K row
            int sw = (seg & 7) << 4;
            const char* gp = kb + (size_t)seg * (QKV_LD * 2) + ((lane * 16) ^ sw);
            gload16(gp, (char*)K_lds + seg * 1024);
        }
    };

    stageQ();
    stageK(kv_begin);

    for (int it = 0; it < ntile; it++) {
        int kv0 = kv_begin + it * 64;

        asm volatile("s_waitcnt vmcnt(0)" ::: "memory");
        fence_barrier();                               // B1: K(it) (and Q on it=0) staged
        __builtin_amdgcn_sched_barrier(0);

        // ---- QK^T: S[16s.., 32hh..] ; A-frags from Q_lds, B-frags from K_lds ----
        fx4 sf[2] = {};
        int ra = s * 16 + l15;
        int qsw = (ra & 7) << 4;
        #pragma unroll
        for (int ks = 0; ks < 16; ks++) {
            bfx8 qa = *(const bfx8*)((const char*)Q_lds + ra * 1024 + ((ks * 64 + l4 * 16) ^ qsw));
            #pragma unroll
            for (int n = 0; n < 2; n++) {
                int krow = hh * 32 + n * 16 + l15;
                int kb2 = (ks * 64 + l4 * 16) ^ ((krow & 7) << 4);
                bfx8 bfr = *(const bfx8*)((const char*)K_lds + krow * 1024 + kb2);
                sf[n] = __builtin_amdgcn_mfma_f32_16x16x32_bf16(qa, bfr, sf[n], 0, 0, 0);
            }
        }
        // causal mask + partial row max over this wave's 32 cols
        float sv[2][4];
        #pragma unroll
        for (int n = 0; n < 2; n++) {
            int col = kv0 + hh * 32 + n * 16 + l15;
            #pragma unroll
            for (int r = 0; r < 4; r++) {
                int row = R0 + s * 16 + l4 * 4 + r;
                sv[n][r] = (col > row) ? -INFINITY : sf[n][r] * rscale;
            }
        }
        #pragma unroll
        for (int r = 0; r < 4; r++) {
            float x = fmaxf(sv[0][r], sv[1][r]);
            x = fmaxf(x, __shfl_xor(x, 1));
            x = fmaxf(x, __shfl_xor(x, 2));
            x = fmaxf(x, __shfl_xor(x, 4));
            x = fmaxf(x, __shfl_xor(x, 8));
            if (l15 == 0) red_lds[s][hh][l4 * 4 + r] = x;
        }
        asm volatile("s_waitcnt lgkmcnt(0)" ::: "memory");
        fence_barrier();                               // B2: red ready; K reads done

        if (it + 1 < ntile) stageK(kv0 + 64);          // K(it+1) hides under softmax+PV

        // ---- V loads for ks=0 (global, L2-hot) issue under softmax ----
        const unsigned short* vrow = vt + (size_t)(cc * 128 + l15) * T_SEQ + kv0 + l4 * 8;
        bfx8 vf0[8];
        #pragma unroll
        for (int n = 0; n < 8; n++)
            vf0[n] = *(const bfx8*)(vrow + (size_t)n * 16 * T_SEQ);

        // ---- softmax finish ----
        float al[4];
        #pragma unroll
        for (int r = 0; r < 4; r++) {
            int row = l4 * 4 + r;
            float mh = fmaxf(red_lds[s][0][row], red_lds[s][1][row]);
            float mn = fmaxf(m_run[r], mh);
            al[r] = __expf(m_run[r] - mn);       // -inf -> 0 (mn finite)
            m_run[r] = mn;
        }
        if (hh == 0 && l15 == 0) {
            #pragma unroll
            for (int r = 0; r < 4; r++) alpha_lds[s * 16 + l4 * 4 + r] = al[r];
        }
        float psum[2][4];
        #pragma unroll
        for (int n = 0; n < 2; n++)
            #pragma unroll
            for (int r = 0; r < 4; r++) {
                float p = __expf(sv[n][r] - m_run[r]);
                int prow = s * 16 + l4 * 4 + r;
                int col = hh * 32 + n * 16 + l15;
                int pb = prow * 128 + ((col * 2) ^ ((prow & 7) << 4));
                *(unsigned short*)((char*)p_lds + pb) = f2bf(p);
                psum[n][r] = p;
            }
        #pragma unroll
        for (int r = 0; r < 4; r++) {
            float x = psum[0][r] + psum[1][r];
            x += __shfl_xor(x, 1); x += __shfl_xor(x, 2);
            x += __shfl_xor(x, 4); x += __shfl_xor(x, 8);
            l_half[r] = l_half[r] * al[r] + x;
        }
        asm volatile("s_waitcnt lgkmcnt(0)" ::: "memory");
        fence_barrier();                               // B3: P+alpha ready
        __builtin_amdgcn_sched_barrier(0);

        // ---- rescale O by alpha of PV rows, then PV (V from registers/global) ----
        float apv[2][4];
        #pragma unroll
        for (int m = 0; m < 2; m++)
            #pragma unroll
            for (int r = 0; r < 4; r++)
                apv[m][r] = alpha_lds[g * 32 + m * 16 + l4 * 4 + r];
        #pragma unroll
        for (int m = 0; m < 2; m++)
            #pragma unroll
            for (int n = 0; n < 8; n++)
                #pragma unroll
                for (int r = 0; r < 4; r++)
                    acc[m][n][r] *= apv[m][r];
        {
            // ks = 0
            bfx8 pa0, pa1;
            {
                int prow0 = g * 32 + l15;
                int prow1 = g * 32 + 16 + l15;
                pa0 = *(const bfx8*)((const char*)p_lds + prow0 * 128 + ((l4 * 16) ^ ((prow0 & 7) << 4)));
                pa1 = *(const bfx8*)((const char*)p_lds + prow1 * 128 + ((l4 * 16) ^ ((prow1 & 7) << 4)));
            }
            bfx8 vf1[8];
            #pragma unroll
            for (int n = 0; n < 8; n++)
                vf1[n] = *(const bfx8*)(vrow + (size_t)n * 16 * T_SEQ + 32);
            #pragma unroll
            for (int n = 0; n < 8; n++) {
                acc[0][n] = __builtin_amdgcn_mfma_f32_16x16x32_bf16(pa0, vf0[n], acc[0][n], 0, 0, 0);
                acc[1][n] = __builtin_amdgcn_mfma_f32_16x16x32_bf16(pa1, vf0[n], acc[1][n], 0, 0, 0);
            }
            // ks = 1
            {
                int prow0 = g * 32 + l15;
                int prow1 = g * 32 + 16 + l15;
                pa0 = *(const bfx8*)((const char*)p_lds + prow0 * 128 + ((64 + l4 * 16) ^ ((prow0 & 7) << 4)));
                pa1 = *(const bfx8*)((const char*)p_lds + prow1 * 128 + ((64 + l4 * 16) ^ ((prow1 & 7) << 4)));
            }
            #pragma unroll
            for (int n = 0; n < 8; n++) {
                acc[0][n] = __builtin_amdgcn_mfma_f32_16x16x32_bf16(pa0, vf1[n], acc[0][n], 0, 0, 0);
                acc[1][n] = __builtin_amdgcn_mfma_f32_16x16x32_bf16(pa1, vf1[n], acc[1][n], 0, 0, 0);
            }
        }
        // no B4: p_lds/alpha_lds reads retire before this wave's next B1; writes
        // happen after next B2 -> B1 provides the separation.
    }

    // ---- store unnormalized O partial (PV roles) ----
    #pragma unroll
    for (int m = 0; m < 2; m++)
        #pragma unroll
        for (int n = 0; n < 8; n++)
            #pragma unroll
            for (int r = 0; r < 4; r++) {
                int rowl = g * 32 + m * 16 + l4 * 4 + r;
                int col = cc * 128 + n * 16 + l15;
                opart[((size_t)bid * 64 + rowl) * DMODEL + col] = f2bf(acc[m][n][r]);
            }
    // ---- m,l store (softmax roles); combine halves' l via red_lds ----
    if (l15 == 0) {
        #pragma unroll
        for (int r = 0; r < 4; r++) red_lds[s][hh][l4 * 4 + r] = l_half[r];
    }
    __syncthreads();
    if (hh == 0 && l15 == 0) {
        #pragma unroll
        for (int r = 0; r < 4; r++) {
            int rr = l4 * 4 + r;
            int rowl = s * 16 + rr;
            lbuf[(size_t)bid * 64 + rowl] = red_lds[s][0][rr] + red_lds[s][1][rr];
            mbuf[(size_t)bid * 64 + rowl] = m_run[r];
        }
    }
}

// ---------------- combine partials across KV chunks ----------------
__global__ __launch_bounds__(256) void combine2_kernel(
    const unsigned short* __restrict__ opart,
    const float* __restrict__ mbuf, const float* __restrict__ lbuf,
    unsigned short* __restrict__ attn, int CH)
{
    int tid = threadIdx.x;
    int row = blockIdx.x * 4 + (tid >> 6);
    int col = (tid & 63) * 8;
    int qi = row >> 6, rowl = row & 63;
    int nch = qi / CH + 1;
    float M = -INFINITY;
    for (int c = 0; c < nch; c++) {
        int pidx = 128 * c - CH * c * (c - 1) / 2 + (qi - CH * c);
        M = fmaxf(M, mbuf[(size_t)pidx * 64 + rowl]);
    }
    float L = 0.f;
    float accv[8] = {0.f,0.f,0.f,0.f,0.f,0.f,0.f,0.f};
    for (int c = 0; c < nch; c++) {
        int pidx = 128 * c - CH * c * (c - 1) / 2 + (qi - CH * c);
        float e = __expf(mbuf[(size_t)pidx * 64 + rowl] - M);
        L += lbuf[(size_t)pidx * 64 + rowl] * e;
        bfx8 v = *(const bfx8*)(opart + ((size_t)pidx * 64 + rowl) * DMODEL + col);
        #pragma unroll
        for (int j = 0; j < 8; j++) accv[j] += e * bf2f((unsigned short)v[j]);
    }
    float invL = 1.0f / L;
    bfx8 o;
    #pragma unroll
    for (int j = 0; j < 8; j++) o[j] = f2bf(accv[j] * invL);
    *(bfx8*)(attn + (size_t)row * DMODEL + col) = o;
}

// ---------------- host launcher ----------------
extern "C" void kernel_launch(void* const* d_in, const int* in_sizes, int n_in,
                              void* d_out, int out_size, void* d_ws, size_t ws_size,
                              hipStream_t stream) {
    const float* h   = (const float*)d_in[0];
    const float* lnw = (const float*)d_in[1];
    const float* lnb = (const float*)d_in[2];
    const float* wq  = (const float*)d_in[3];
    const float* wk  = (const float*)d_in[4];
    const float* wv  = (const float*)d_in[5];
    const float* wo  = (const float*)d_in[6];
    float* out = (float*)d_out;

    char* ws = (char*)d_ws;
    size_t off = 0;
    auto alloc = [&](size_t bytes) {
        char* p = ws + off;
        off += (bytes + 255) & ~(size_t)255;
        return p;
    };
    const size_t TD2 = (size_t)T_SEQ * DMODEL * 2;
    const size_t W2  = (size_t)DMODEL * DMODEL * 2;   // 512KB, 256-aligned
    unsigned short* hn   = (unsigned short*)alloc(TD2);
    unsigned short* wqkv = (unsigned short*)alloc(3 * W2);   // stacked [wq;wk;wv], contiguous
    unsigned short* wob  = (unsigned short*)alloc(W2);
    unsigned short* qkvb = (unsigned short*)alloc((size_t)T_SEQ * QKV_LD * 2);  // fused QKV [T][1536]
    unsigned short* vtb  = (unsigned short*)alloc(TD2);
    unsigned short* attnb= (unsigned short*)alloc(TD2);

    // KV chunking: CH kv-tiles (64 rows each) per chunk.
    // blocks NBLK = sum_{qi=0..127} ceil((qi+1)/CH); opart = NBLK*64*512*2 bytes.
    int CH = 8, NBLK = 1088;     // 8*(1+..+16) = 1088, %8==0
    {
        size_t need = off + 2 * ((1088u * 64 * 4 + 255) & ~(size_t)255)
                    + (((size_t)1088 * 64 * 512 * 2 + 255) & ~(size_t)255);
        if (need > ws_size) { CH = 16; NBLK = 576; }   // 16*(1+..+8)=576, %8==0
    }
    float* mbuf = (float*)alloc((size_t)NBLK * 64 * 4);
    float* lbuf = (float*)alloc((size_t)NBLK * 64 * 4);
    unsigned short* opart = (unsigned short*)alloc((size_t)NBLK * 64 * 512 * 2);

    cvt_bf16_kernel<<<dim3(128), dim3(256), 0, stream>>>(wq, wqkv,              DMODEL * DMODEL);
    cvt_bf16_kernel<<<dim3(128), dim3(256), 0, stream>>>(wk, wqkv + DMODEL*DMODEL,   DMODEL * DMODEL);
    cvt_bf16_kernel<<<dim3(128), dim3(256), 0, stream>>>(wv, wqkv + 2*DMODEL*DMODEL, DMODEL * DMODEL);
    cvt_bf16_kernel<<<dim3(128), dim3(256), 0, stream>>>(wo, wob, DMODEL * DMODEL);

    layernorm_kernel<<<dim3(T_SEQ / 4), dim3(256), 0, stream>>>(h, lnw, lnb, hn);

    // fused QKV projection: [T,512] @ [1536,512]^T -> [T,1536]
    gemm_bt_kernel<0><<<dim3(QKV_LD / 128, T_SEQ / 128), dim3(256), 0, stream>>>(
        hn, wqkv, qkvb, nullptr, nullptr, T_SEQ, QKV_LD, DMODEL);

    // V (cols 1024..1535 of qkvb) -> Vt [512][T]
    transpose_kernel<<<dim3(T_SEQ / 64, DMODEL / 64), dim3(256), 0, stream>>>(
        qkvb + 2 * DMODEL, vtb, QKV_LD);

    flash4_kernel<<<dim3(NBLK), dim3(512), 0, stream>>>(
        qkvb, qkvb + DMODEL, vtb, opart, mbuf, lbuf, CH, NBLK);

    combine2_kernel<<<dim3(T_SEQ / 4), dim3(256), 0, stream>>>(opart, mbuf, lbuf, attnb, CH);

    gemm_bt_kernel<1><<<dim3(DMODEL / 128, T_SEQ / 128), dim3(256), 0, stream>>>(
        attnb, wob, nullptr, out, h, T_SEQ, DMODEL, DMODEL);
}